// Round 1
// baseline (3378.172 us; speedup 1.0000x reference)
//
#include <hip/hip_runtime.h>

#define D 128
#define GR 32   // rows per GEMM block

// H[r][c] = relu( sum_k X[r][k] * W[k][c] + b[c] ), X:[n,128] W:[128,128]
__global__ __launch_bounds__(256) void gemm_relu_kernel(
    const float* __restrict__ X, const float* __restrict__ W,
    const float* __restrict__ bias, float* __restrict__ H, int nrows)
{
    __shared__ float Ws[D * D];     // 64 KiB
    __shared__ float Xs[GR][D];     // 16 KiB
    const int tid = threadIdx.x;

    // stage W (16384 floats = 4096 float4)
    {
        const float4* W4 = (const float4*)W;
        float4* Ws4 = (float4*)Ws;
        #pragma unroll
        for (int i = 0; i < 16; ++i) Ws4[tid + 256 * i] = W4[tid + 256 * i];
    }
    const int row0 = blockIdx.x * GR;
    // stage X rows (32 rows x 128 = 1024 float4)
    {
        const float4* X4 = (const float4*)(X + (size_t)row0 * D);
        float4* Xs4 = (float4*)&Xs[0][0];
        #pragma unroll
        for (int i = 0; i < 4; ++i) {
            int idx = tid + 256 * i;            // float4 index; 32 float4 per row
            if (row0 + (idx >> 5) < nrows) Xs4[idx] = X4[idx];
        }
    }
    __syncthreads();

    const int ct = (tid & 31) * 4;   // 32 col-tiles of 4
    const int rt = (tid >> 5) * 4;   // 8 row-tiles of 4
    float acc[4][4];
    #pragma unroll
    for (int r = 0; r < 4; ++r)
        #pragma unroll
        for (int c = 0; c < 4; ++c) acc[r][c] = 0.f;

    #pragma unroll 8
    for (int k = 0; k < D; ++k) {
        const float4 wv = *(const float4*)&Ws[k * D + ct];
        #pragma unroll
        for (int r = 0; r < 4; ++r) {
            const float xv = Xs[rt + r][k];
            acc[r][0] = fmaf(xv, wv.x, acc[r][0]);
            acc[r][1] = fmaf(xv, wv.y, acc[r][1]);
            acc[r][2] = fmaf(xv, wv.z, acc[r][2]);
            acc[r][3] = fmaf(xv, wv.w, acc[r][3]);
        }
    }

    const float4 bv = *(const float4*)&bias[ct];
    #pragma unroll
    for (int r = 0; r < 4; ++r) {
        const int row = row0 + rt + r;
        if (row < nrows) {
            float4 o;
            o.x = fmaxf(acc[r][0] + bv.x, 0.f);
            o.y = fmaxf(acc[r][1] + bv.y, 0.f);
            o.z = fmaxf(acc[r][2] + bv.z, 0.f);
            o.w = fmaxf(acc[r][3] + bv.w, 0.f);
            *(float4*)&H[(size_t)row * D + ct] = o;
        }
    }
}

// out[dst[e]] += H[src[e]]  (row-wise, 32 threads/edge, float4 each)
__global__ __launch_bounds__(256) void scatter_add_kernel(
    const float* __restrict__ H, const int* __restrict__ src,
    const int* __restrict__ dst, float* __restrict__ out, int nedges)
{
    const long long t = (long long)blockIdx.x * 256 + threadIdx.x;
    const int e = (int)(t >> 5);
    if (e >= nedges) return;
    const int c = ((int)t & 31) * 4;
    const int s = src[e];
    const int d = dst[e];
    const float4 v = *(const float4*)&H[(size_t)s * D + c];
    float* o = &out[(size_t)d * D + c];
    atomicAdd(o + 0, v.x);
    atomicAdd(o + 1, v.y);
    atomicAdd(o + 2, v.z);
    atomicAdd(o + 3, v.w);
}

extern "C" void kernel_launch(void* const* d_in, const int* in_sizes, int n_in,
                              void* d_out, int out_size, void* d_ws, size_t ws_size,
                              hipStream_t stream)
{
    const float* x_user   = (const float*)d_in[0];
    // d_in[1] = x_item (unused by the math: both relations source from users)
    const int*   ei_fol   = (const int*)d_in[2];
    const int*   ei_rat   = (const int*)d_in[3];
    const float* W0f = (const float*)d_in[4];
    const float* b0f = (const float*)d_in[5];
    // d_in[6], d_in[7] = W0_rates/b0_rates: dead code (new_i0 never consumed)
    const float* W1f = (const float*)d_in[8];
    const float* b1f = (const float*)d_in[9];
    const float* W1r = (const float*)d_in[10];
    const float* b1r = (const float*)d_in[11];

    const int n  = in_sizes[0] / D;     // 100000
    const int Ef = in_sizes[2] / 2;     // 600000
    const int Er = in_sizes[3] / 2;

    float* out_u = (float*)d_out;
    float* out_i = out_u + (size_t)n * D;

    float* Hbuf = (float*)d_ws;         // [n,128] scratch (51.2 MB)
    float* U1   = out_i;                // stage new_u0 in out_i's slot; re-zeroed later

    const size_t rowbytes = (size_t)n * D * sizeof(float);

    // zero both output halves (harness poisons with 0xAA)
    hipMemsetAsync(d_out, 0, 2 * rowbytes, stream);

    const dim3 blk(256);
    const int gemm_grid = (n + GR - 1) / GR;
    const int sc_grid_f = (int)(((long long)Ef * 32 + 255) / 256);
    const int sc_grid_r = (int)(((long long)Er * 32 + 255) / 256);

    // Layer 0 (follows only; rates output is dead)
    gemm_relu_kernel<<<gemm_grid, blk, 0, stream>>>(x_user, W0f, b0f, Hbuf, n);
    scatter_add_kernel<<<sc_grid_f, blk, 0, stream>>>(Hbuf, ei_fol, ei_fol + Ef, U1, Ef);

    // Layer 1, follows: out_u
    gemm_relu_kernel<<<gemm_grid, blk, 0, stream>>>(U1, W1f, b1f, Hbuf, n);
    scatter_add_kernel<<<sc_grid_f, blk, 0, stream>>>(Hbuf, ei_fol, ei_fol + Ef, out_u, Ef);

    // Layer 1, rates: out_i (reuses U1's slot; zero it first, after GEMM consumed U1)
    gemm_relu_kernel<<<gemm_grid, blk, 0, stream>>>(U1, W1r, b1r, Hbuf, n);
    hipMemsetAsync(out_i, 0, rowbytes, stream);
    scatter_add_kernel<<<sc_grid_r, blk, 0, stream>>>(Hbuf, ei_rat, ei_rat + Er, out_i, Er);
}

// Round 2
// 633.654 us; speedup vs baseline: 5.3313x; 5.3313x over previous
//
#include <hip/hip_runtime.h>

#define D 128
#define GR 32           // rows per GEMM block
#define SCAN_CHUNK 2048 // elements per scan block (256 thr x 8)

// ---------------- GEMM + ReLU:  H = relu(X @ W + b) ----------------
__global__ __launch_bounds__(256) void gemm_relu_kernel(
    const float* __restrict__ X, const float* __restrict__ W,
    const float* __restrict__ bias, float* __restrict__ H, int nrows)
{
    __shared__ float Ws[D * D];     // 64 KiB
    __shared__ float Xs[GR][D];     // 16 KiB
    const int tid = threadIdx.x;

    {   // stage W (4096 float4)
        const float4* W4 = (const float4*)W;
        float4* Ws4 = (float4*)Ws;
        #pragma unroll
        for (int i = 0; i < 16; ++i) Ws4[tid + 256 * i] = W4[tid + 256 * i];
    }
    const int row0 = blockIdx.x * GR;
    {   // stage X rows (1024 float4)
        const float4* X4 = (const float4*)(X + (size_t)row0 * D);
        float4* Xs4 = (float4*)&Xs[0][0];
        #pragma unroll
        for (int i = 0; i < 4; ++i) {
            int idx = tid + 256 * i;
            if (row0 + (idx >> 5) < nrows) Xs4[idx] = X4[idx];
        }
    }
    __syncthreads();

    const int ct = (tid & 31) * 4;
    const int rt = (tid >> 5) * 4;
    float acc[4][4];
    #pragma unroll
    for (int r = 0; r < 4; ++r)
        #pragma unroll
        for (int c = 0; c < 4; ++c) acc[r][c] = 0.f;

    for (int k0 = 0; k0 < D; k0 += 4) {
        float4 xv[4];
        #pragma unroll
        for (int r = 0; r < 4; ++r) xv[r] = *(const float4*)&Xs[rt + r][k0];
        #pragma unroll
        for (int kk = 0; kk < 4; ++kk) {
            const float4 wv = *(const float4*)&Ws[(k0 + kk) * D + ct];
            #pragma unroll
            for (int r = 0; r < 4; ++r) {
                const float x = ((const float*)&xv[r])[kk];
                acc[r][0] = fmaf(x, wv.x, acc[r][0]);
                acc[r][1] = fmaf(x, wv.y, acc[r][1]);
                acc[r][2] = fmaf(x, wv.z, acc[r][2]);
                acc[r][3] = fmaf(x, wv.w, acc[r][3]);
            }
        }
    }

    const float4 bv = *(const float4*)&bias[ct];
    #pragma unroll
    for (int r = 0; r < 4; ++r) {
        const int row = row0 + rt + r;
        if (row < nrows) {
            float4 o;
            o.x = fmaxf(acc[r][0] + bv.x, 0.f);
            o.y = fmaxf(acc[r][1] + bv.y, 0.f);
            o.z = fmaxf(acc[r][2] + bv.z, 0.f);
            o.w = fmaxf(acc[r][3] + bv.w, 0.f);
            *(float4*)&H[(size_t)row * D + ct] = o;
        }
    }
}

// ---------------- CSR build ----------------
__global__ __launch_bounds__(256) void hist_kernel(
    const int* __restrict__ dst, int* __restrict__ deg, int n)
{
    for (int i = blockIdx.x * 256 + threadIdx.x; i < n; i += gridDim.x * 256)
        atomicAdd(&deg[dst[i]], 1);
}

// per-chunk sums
__global__ __launch_bounds__(256) void scan_partial_kernel(
    const int* __restrict__ deg, int* __restrict__ bsum, int n)
{
    __shared__ int red[256];
    const int tid = threadIdx.x;
    const int base = blockIdx.x * SCAN_CHUNK + tid * 8;
    int s = 0;
    #pragma unroll
    for (int i = 0; i < 8; ++i) { int idx = base + i; s += (idx < n) ? deg[idx] : 0; }
    red[tid] = s; __syncthreads();
    for (int off = 128; off > 0; off >>= 1) {
        if (tid < off) red[tid] += red[tid + off];
        __syncthreads();
    }
    if (tid == 0) bsum[blockIdx.x] = red[0];
}

// exclusive scan of chunk sums (nb <= 64), one wave; also writes rowptr[n]=total
__global__ void scan_bsum_kernel(const int* __restrict__ bsum, int* __restrict__ boff,
                                 int nb, int* __restrict__ rowptr_end, int total)
{
    const int lane = threadIdx.x;
    int v = (lane < nb) ? bsum[lane] : 0;
    int incl = v;
    for (int off = 1; off < 64; off <<= 1) {
        int y = __shfl_up(incl, off, 64);
        if (lane >= off) incl += y;
    }
    if (lane < nb) boff[lane] = incl - v;
    if (lane == 0) *rowptr_end = total;
}

// exclusive scan within chunk + chunk offset -> rowptr[0..n)
__global__ __launch_bounds__(256) void scan_write_kernel(
    const int* __restrict__ deg, const int* __restrict__ boff,
    int* __restrict__ rowptr, int n)
{
    __shared__ int ts[256];
    const int tid = threadIdx.x;
    const int base = blockIdx.x * SCAN_CHUNK + tid * 8;
    int v[8]; int s = 0;
    #pragma unroll
    for (int i = 0; i < 8; ++i) { int idx = base + i; v[i] = (idx < n) ? deg[idx] : 0; s += v[i]; }
    ts[tid] = s; __syncthreads();
    int incl = s;
    for (int off = 1; off < 256; off <<= 1) {
        int y = (tid >= off) ? ts[tid - off] : 0;
        __syncthreads();
        incl += y; ts[tid] = incl;
        __syncthreads();
    }
    int run = boff[blockIdx.x] + incl - s;   // exclusive prefix of this thread's 8
    #pragma unroll
    for (int i = 0; i < 8; ++i) {
        int idx = base + i;
        if (idx < n) { rowptr[idx] = run; run += v[i]; }
    }
}

// scatter edges into dst-sorted order: esrc[pos] = src[e]
__global__ __launch_bounds__(256) void fill_kernel(
    const int* __restrict__ src, const int* __restrict__ dst,
    int* __restrict__ cursor, int* __restrict__ esrc, int n)
{
    for (int e = blockIdx.x * 256 + threadIdx.x; e < n; e += gridDim.x * 256) {
        int p = atomicAdd(&cursor[dst[e]], 1);
        esrc[p] = src[e];
    }
}

// ---------------- segmented sum: out[r] = sum over incoming edges of H[src] ----------------
__global__ __launch_bounds__(256) void segsum_kernel(
    const float* __restrict__ H, const int* __restrict__ rowptr,
    const int* __restrict__ esrc, float* __restrict__ out, int nrows)
{
    const int t = blockIdx.x * 256 + threadIdx.x;
    const int row = t >> 5;
    if (row >= nrows) return;
    const int c = (t & 31) * 4;
    const int beg = rowptr[row], end = rowptr[row + 1];
    float4 acc = {0.f, 0.f, 0.f, 0.f};
    for (int j = beg; j < end; ++j) {
        const int s = esrc[j];
        const float4 v = *(const float4*)&H[(size_t)s * D + c];
        acc.x += v.x; acc.y += v.y; acc.z += v.z; acc.w += v.w;
    }
    *(float4*)&out[(size_t)row * D + c] = acc;
}

// ---------------- host-side orchestration ----------------
static inline size_t align16(size_t x) { return (x + 15) & ~(size_t)15; }

static void build_csr(const int* src, const int* dst, int E, int n,
                      int* deg, int* bsum, int* boff, int* cursor,
                      int* rowptr, int* esrc, hipStream_t stream)
{
    const int nb = (n + SCAN_CHUNK - 1) / SCAN_CHUNK;   // 49 for n=100000 (<=64 required)
    hipMemsetAsync(deg, 0, (size_t)n * sizeof(int), stream);
    hist_kernel<<<1024, 256, 0, stream>>>(dst, deg, E);
    scan_partial_kernel<<<nb, 256, 0, stream>>>(deg, bsum, n);
    scan_bsum_kernel<<<1, 64, 0, stream>>>(bsum, boff, nb, rowptr + n, E);
    scan_write_kernel<<<nb, 256, 0, stream>>>(deg, boff, rowptr, n);
    hipMemcpyAsync(cursor, rowptr, (size_t)n * sizeof(int),
                   hipMemcpyDeviceToDevice, stream);
    fill_kernel<<<1024, 256, 0, stream>>>(src, dst, cursor, esrc, E);
}

extern "C" void kernel_launch(void* const* d_in, const int* in_sizes, int n_in,
                              void* d_out, int out_size, void* d_ws, size_t ws_size,
                              hipStream_t stream)
{
    const float* x_user = (const float*)d_in[0];
    // d_in[1] = x_item: unused (both relations source from users)
    const int*   ei_fol = (const int*)d_in[2];
    const int*   ei_rat = (const int*)d_in[3];
    const float* W0f = (const float*)d_in[4];
    const float* b0f = (const float*)d_in[5];
    // d_in[6..7] = W0_rates/b0_rates: dead (layer-0 item output never consumed)
    const float* W1f = (const float*)d_in[8];
    const float* b1f = (const float*)d_in[9];
    const float* W1r = (const float*)d_in[10];
    const float* b1r = (const float*)d_in[11];

    const int n  = in_sizes[0] / D;   // 100000
    const int Ef = in_sizes[2] / 2;   // 600000
    const int Er = in_sizes[3] / 2;

    float* out_u = (float*)d_out;
    float* out_i = out_u + (size_t)n * D;

    // workspace layout (~58 MB)
    char* ws = (char*)d_ws;
    size_t off = 0;
    float* H      = (float*)(ws + off); off = align16(off + (size_t)n * D * sizeof(float));
    int* rowptr_f = (int*)  (ws + off); off = align16(off + (size_t)(n + 1) * sizeof(int));
    int* rowptr_r = (int*)  (ws + off); off = align16(off + (size_t)(n + 1) * sizeof(int));
    int* esrc_f   = (int*)  (ws + off); off = align16(off + (size_t)Ef * sizeof(int));
    int* esrc_r   = (int*)  (ws + off); off = align16(off + (size_t)Er * sizeof(int));
    int* deg      = (int*)  (ws + off); off = align16(off + (size_t)n * sizeof(int));
    int* cursor   = (int*)  (ws + off); off = align16(off + (size_t)n * sizeof(int));
    int* bsum     = (int*)  (ws + off); off = align16(off + 64 * sizeof(int));
    int* boff     = (int*)  (ws + off); off = align16(off + 64 * sizeof(int));
    (void)ws_size;

    // CSR by destination for each relation (follows reused by both layers)
    build_csr(ei_fol, ei_fol + Ef, Ef, n, deg, bsum, boff, cursor, rowptr_f, esrc_f, stream);
    build_csr(ei_rat, ei_rat + Er, Er, n, deg, bsum, boff, cursor, rowptr_r, esrc_r, stream);

    const dim3 blk(256);
    const int gemm_grid = (n + GR - 1) / GR;
    const int seg_grid  = (int)(((long long)n * 32 + 255) / 256);

    float* U1 = out_i;   // stage layer-0 user output in out_i's slot (overwritten at the end)

    // Layer 0, follows (rates output is dead)
    gemm_relu_kernel<<<gemm_grid, blk, 0, stream>>>(x_user, W0f, b0f, H, n);
    segsum_kernel<<<seg_grid, blk, 0, stream>>>(H, rowptr_f, esrc_f, U1, n);

    // Layer 1, follows -> out_u
    gemm_relu_kernel<<<gemm_grid, blk, 0, stream>>>(U1, W1f, b1f, H, n);
    segsum_kernel<<<seg_grid, blk, 0, stream>>>(H, rowptr_f, esrc_f, out_u, n);

    // Layer 1, rates -> out_i (overwrites U1 only after H is computed)
    gemm_relu_kernel<<<gemm_grid, blk, 0, stream>>>(U1, W1r, b1r, H, n);
    segsum_kernel<<<seg_grid, blk, 0, stream>>>(H, rowptr_r, esrc_r, out_i, n);
}

// Round 3
// 504.436 us; speedup vs baseline: 6.6969x; 1.2562x over previous
//
#include <hip/hip_runtime.h>

#define D 128
#define SCAN_CHUNK 2048

typedef __attribute__((ext_vector_type(8))) short bf16x8;
typedef __attribute__((ext_vector_type(4))) float f32x4;

static __device__ __forceinline__ unsigned short f2bf(float f) {
    union { float f; unsigned u; } v; v.f = f;
    unsigned r = (v.u + 0x7fffu + ((v.u >> 16) & 1u)) >> 16;   // RNE
    return (unsigned short)r;
}
static __device__ __forceinline__ float bf2f(unsigned short s) {
    union { unsigned u; float f; } v; v.u = ((unsigned)s) << 16;
    return v.f;
}

// ---------------- GEMM + ReLU via MFMA:  H(bf16) = relu(X(f32) @ W(f32) + b) ----
// BM=32, BN=128, K=128. Split-bf16 X (hi+lo -> 2 MFMAs), bf16 W (hi only).
// LDS 48KB -> 3 blocks/CU. XOR swizzle (elem ^= (row&7)<<3) kills bank conflicts.
__global__ __launch_bounds__(256) void gemm_relu_bf16(
    const float* __restrict__ X, const float* __restrict__ W,
    const float* __restrict__ bias, unsigned short* __restrict__ H, int nrows)
{
    __shared__ unsigned short Xh[32 * D];   // 8 KB
    __shared__ unsigned short Xl[32 * D];   // 8 KB
    __shared__ unsigned short Wh[128 * D];  // 32 KB, transposed: Wh[n][k]
    const int tid = threadIdx.x;
    const int w = tid >> 6, l = tid & 63;
    const int row0 = blockIdx.x * 32;

    // stage W transposed (B-frag needs 8 consecutive k at fixed n)
    {
        const int n = ((w & 1) << 6) + l;             // coalesced 256B rows of W
        #pragma unroll
        for (int i = 0; i < 8; ++i) {
            const int k0 = ((w >> 1) << 3) + (i << 4);
            bf16x8 hv;
            #pragma unroll
            for (int j = 0; j < 8; ++j)
                hv[j] = (short)f2bf(W[(size_t)(k0 + j) * D + n]);
            *(bf16x8*)&Wh[n * D + (k0 ^ ((n & 7) << 3))] = hv;
        }
    }
    // stage X rows, hi + lo residual
    {
        const int k0 = (l & 15) << 3;
        #pragma unroll
        for (int i = 0; i < 2; ++i) {
            const int r = ((w + (i << 2)) << 2) + (l >> 4);   // 0..31
            bf16x8 hv, lv;
            if (row0 + r < nrows) {
                const float* xp = X + (size_t)(row0 + r) * D + k0;
                #pragma unroll
                for (int j = 0; j < 8; ++j) {
                    float x = xp[j];
                    unsigned short h = f2bf(x);
                    hv[j] = (short)h;
                    lv[j] = (short)f2bf(x - bf2f(h));
                }
            } else {
                #pragma unroll
                for (int j = 0; j < 8; ++j) { hv[j] = 0; lv[j] = 0; }
            }
            const int sw = k0 ^ ((r & 7) << 3);
            *(bf16x8*)&Xh[r * D + sw] = hv;
            *(bf16x8*)&Xl[r * D + sw] = lv;
        }
    }
    __syncthreads();

    const int rtile = (w >> 1) << 4;   // wave's row-tile base (0/16)
    const int c0 = (w & 1) << 6;       // wave's col base (0/64)
    const int ra = rtile + (l & 15);   // A row for this lane
    f32x4 acc[4] = {};

    #pragma unroll
    for (int kb = 0; kb < 4; ++kb) {
        const int kk0 = (kb << 5) + ((l >> 4) << 3);
        const int swa = kk0 ^ ((ra & 7) << 3);
        const bf16x8 ah = *(const bf16x8*)&Xh[ra * D + swa];
        const bf16x8 al = *(const bf16x8*)&Xl[ra * D + swa];
        #pragma unroll
        for (int ct = 0; ct < 4; ++ct) {
            const int n = c0 + (ct << 4) + (l & 15);
            const bf16x8 bh = *(const bf16x8*)&Wh[n * D + (kk0 ^ ((n & 7) << 3))];
            acc[ct] = __builtin_amdgcn_mfma_f32_16x16x32_bf16(ah, bh, acc[ct], 0, 0, 0);
            acc[ct] = __builtin_amdgcn_mfma_f32_16x16x32_bf16(al, bh, acc[ct], 0, 0, 0);
        }
    }

    // epilogue: +bias, relu, store bf16. D-layout: row=(l>>4)*4+j, col=l&15
    #pragma unroll
    for (int ct = 0; ct < 4; ++ct) {
        const int col = c0 + (ct << 4) + (l & 15);
        const float bv = bias[col];
        #pragma unroll
        for (int j = 0; j < 4; ++j) {
            const int r = row0 + rtile + ((l >> 4) << 2) + j;
            if (r < nrows)
                H[(size_t)r * D + col] = f2bf(fmaxf(acc[ct][j] + bv, 0.f));
        }
    }
}

// ---------------- segmented sum over bf16 H -> fp32 out ----------------
__global__ __launch_bounds__(256) void segsum_bf16(
    const unsigned short* __restrict__ H, const int* __restrict__ rowptr,
    const int* __restrict__ esrc, float* __restrict__ out, int nrows)
{
    const int t = blockIdx.x * 256 + threadIdx.x;
    const int row = t >> 4;
    if (row >= nrows) return;
    const int c = (t & 15) << 3;           // 8 bf16 elems per lane
    float a[8] = {0.f,0.f,0.f,0.f,0.f,0.f,0.f,0.f};
    const int beg = rowptr[row], end = rowptr[row + 1];
    for (int j = beg; j < end; ++j) {
        const int s = esrc[j];
        const uint4 v = *(const uint4*)(H + (size_t)s * D + c);
        const unsigned dw[4] = {v.x, v.y, v.z, v.w};
        #pragma unroll
        for (int d2 = 0; d2 < 4; ++d2) {
            union { unsigned u; float f; } lo, hi;
            lo.u = dw[d2] << 16;
            hi.u = dw[d2] & 0xffff0000u;
            a[2 * d2]     += lo.f;
            a[2 * d2 + 1] += hi.f;
        }
    }
    float4 o0 = {a[0], a[1], a[2], a[3]};
    float4 o1 = {a[4], a[5], a[6], a[7]};
    *(float4*)(out + (size_t)row * D + c)     = o0;
    *(float4*)(out + (size_t)row * D + c + 4) = o1;
}

// ---------------- CSR build (both relations fused per stage) ----------------
__global__ __launch_bounds__(256) void hist2_kernel(
    const int* __restrict__ dstf, const int* __restrict__ dstr,
    int Ef, int Er, int* __restrict__ degf, int* __restrict__ degr)
{
    const int tot = Ef + Er;
    for (int i = blockIdx.x * 256 + threadIdx.x; i < tot; i += gridDim.x * 256) {
        if (i < Ef) atomicAdd(&degf[dstf[i]], 1);
        else        atomicAdd(&degr[dstr[i - Ef]], 1);
    }
}

__global__ __launch_bounds__(256) void scan_partial2_kernel(
    const int* __restrict__ degf, const int* __restrict__ degr,
    int* __restrict__ bsumf, int* __restrict__ bsumr, int n, int nb)
{
    __shared__ int red[256];
    const int tid = threadIdx.x;
    int b = blockIdx.x;
    const int* deg = (b < nb) ? degf : degr;
    int* bs = (b < nb) ? bsumf : bsumr;
    if (b >= nb) b -= nb;
    const int base = b * SCAN_CHUNK + tid * 8;
    int s = 0;
    #pragma unroll
    for (int i = 0; i < 8; ++i) { int idx = base + i; s += (idx < n) ? deg[idx] : 0; }
    red[tid] = s; __syncthreads();
    for (int off = 128; off > 0; off >>= 1) {
        if (tid < off) red[tid] += red[tid + off];
        __syncthreads();
    }
    if (tid == 0) bs[b] = red[0];
}

__global__ void scan_bsum2_kernel(
    const int* __restrict__ bsumf, const int* __restrict__ bsumr,
    int* __restrict__ bofff, int* __restrict__ boffr, int nb,
    int* __restrict__ rpf_end, int* __restrict__ rpr_end, int Ef, int Er)
{
    const int wv = threadIdx.x >> 6, lane = threadIdx.x & 63;
    const int* bs = wv ? bsumr : bsumf;
    int* bo = wv ? boffr : bofff;
    int v = (lane < nb) ? bs[lane] : 0;
    int incl = v;
    for (int off = 1; off < 64; off <<= 1) {
        int y = __shfl_up(incl, off, 64);
        if (lane >= off) incl += y;
    }
    if (lane < nb) bo[lane] = incl - v;
    if (lane == 0) { if (wv) *rpr_end = Er; else *rpf_end = Ef; }
}

__global__ __launch_bounds__(256) void scan_write2_kernel(
    const int* __restrict__ degf, const int* __restrict__ degr,
    const int* __restrict__ bofff, const int* __restrict__ boffr,
    int* __restrict__ rpf, int* __restrict__ rpr,
    int* __restrict__ curf, int* __restrict__ curr, int n, int nb)
{
    __shared__ int ts[256];
    const int tid = threadIdx.x;
    int b = blockIdx.x;
    const int* deg; const int* boff; int* rp; int* cur;
    if (b < nb) { deg = degf; boff = bofff; rp = rpf; cur = curf; }
    else        { deg = degr; boff = boffr; rp = rpr; cur = curr; b -= nb; }
    const int base = b * SCAN_CHUNK + tid * 8;
    int v[8]; int s = 0;
    #pragma unroll
    for (int i = 0; i < 8; ++i) { int idx = base + i; v[i] = (idx < n) ? deg[idx] : 0; s += v[i]; }
    ts[tid] = s; __syncthreads();
    int incl = s;
    for (int off = 1; off < 256; off <<= 1) {
        int y = (tid >= off) ? ts[tid - off] : 0;
        __syncthreads();
        incl += y; ts[tid] = incl;
        __syncthreads();
    }
    int run = boff[b] + incl - s;
    #pragma unroll
    for (int i = 0; i < 8; ++i) {
        int idx = base + i;
        if (idx < n) { rp[idx] = run; cur[idx] = run; run += v[i]; }
    }
}

__global__ __launch_bounds__(256) void fill2_kernel(
    const int* __restrict__ eif, const int* __restrict__ eir,
    int Ef, int Er, int* __restrict__ curf, int* __restrict__ curr,
    int* __restrict__ esrcf, int* __restrict__ esrcr)
{
    const int tot = Ef + Er;
    for (int i = blockIdx.x * 256 + threadIdx.x; i < tot; i += gridDim.x * 256) {
        if (i < Ef) {
            int p = atomicAdd(&curf[eif[Ef + i]], 1);
            esrcf[p] = eif[i];
        } else {
            int e = i - Ef;
            int p = atomicAdd(&curr[eir[Er + e]], 1);
            esrcr[p] = eir[e];
        }
    }
}

// ---------------- host orchestration ----------------
static inline size_t align16(size_t x) { return (x + 15) & ~(size_t)15; }

extern "C" void kernel_launch(void* const* d_in, const int* in_sizes, int n_in,
                              void* d_out, int out_size, void* d_ws, size_t ws_size,
                              hipStream_t stream)
{
    const float* x_user = (const float*)d_in[0];
    // d_in[1] = x_item: unused (both relations source from users)
    const int*   ei_fol = (const int*)d_in[2];
    const int*   ei_rat = (const int*)d_in[3];
    const float* W0f = (const float*)d_in[4];
    const float* b0f = (const float*)d_in[5];
    // d_in[6..7]: W0_rates/b0_rates dead (layer-0 item output never consumed)
    const float* W1f = (const float*)d_in[8];
    const float* b1f = (const float*)d_in[9];
    const float* W1r = (const float*)d_in[10];
    const float* b1r = (const float*)d_in[11];

    const int n  = in_sizes[0] / D;   // 100000
    const int Ef = in_sizes[2] / 2;   // 600000
    const int Er = in_sizes[3] / 2;
    const int nb = (n + SCAN_CHUNK - 1) / SCAN_CHUNK;   // 49 (<=64)

    float* out_u = (float*)d_out;
    float* out_i = out_u + (size_t)n * D;
    float* U1 = out_i;   // fp32 layer-0 user output staged in out_i's slot

    // workspace (~34 MB)
    char* ws = (char*)d_ws;
    size_t off = 0;
    unsigned short* H = (unsigned short*)(ws + off); off = align16(off + (size_t)n * D * sizeof(unsigned short));
    int* rpf   = (int*)(ws + off); off = align16(off + (size_t)(n + 1) * sizeof(int));
    int* rpr   = (int*)(ws + off); off = align16(off + (size_t)(n + 1) * sizeof(int));
    int* esrcf = (int*)(ws + off); off = align16(off + (size_t)Ef * sizeof(int));
    int* esrcr = (int*)(ws + off); off = align16(off + (size_t)Er * sizeof(int));
    int* deg2  = (int*)(ws + off); off = align16(off + (size_t)2 * n * sizeof(int));
    int* cur2  = (int*)(ws + off); off = align16(off + (size_t)2 * n * sizeof(int));
    int* bsumf = (int*)(ws + off); off = align16(off + 64 * sizeof(int));
    int* bsumr = (int*)(ws + off); off = align16(off + 64 * sizeof(int));
    int* bofff = (int*)(ws + off); off = align16(off + 64 * sizeof(int));
    int* boffr = (int*)(ws + off); off = align16(off + 64 * sizeof(int));
    (void)ws_size;
    int* degf = deg2, *degr = deg2 + n;
    int* curf = cur2, *curr = cur2 + n;

    const dim3 blk(256);
    const int gemm_grid = (n + 31) / 32;                      // 3125
    const int seg_grid  = (int)(((long long)n * 16 + 255) / 256);  // 6250

    // CSR build (both relations)
    hipMemsetAsync(deg2, 0, (size_t)2 * n * sizeof(int), stream);
    hist2_kernel<<<1024, blk, 0, stream>>>(ei_fol + Ef, ei_rat + Er, Ef, Er, degf, degr);
    scan_partial2_kernel<<<2 * nb, blk, 0, stream>>>(degf, degr, bsumf, bsumr, n, nb);
    scan_bsum2_kernel<<<1, 128, 0, stream>>>(bsumf, bsumr, bofff, boffr, nb,
                                             rpf + n, rpr + n, Ef, Er);
    scan_write2_kernel<<<2 * nb, blk, 0, stream>>>(degf, degr, bofff, boffr,
                                                   rpf, rpr, curf, curr, n, nb);
    fill2_kernel<<<1024, blk, 0, stream>>>(ei_fol, ei_rat, Ef, Er, curf, curr, esrcf, esrcr);

    // Layer 0, follows (rates output is dead)
    gemm_relu_bf16<<<gemm_grid, blk, 0, stream>>>(x_user, W0f, b0f, H, n);
    segsum_bf16<<<seg_grid, blk, 0, stream>>>(H, rpf, esrcf, U1, n);

    // Layer 1, follows -> out_u
    gemm_relu_bf16<<<gemm_grid, blk, 0, stream>>>(U1, W1f, b1f, H, n);
    segsum_bf16<<<seg_grid, blk, 0, stream>>>(H, rpf, esrcf, out_u, n);

    // Layer 1, rates -> out_i (overwrites U1 slot only after GEMM consumed it)
    gemm_relu_bf16<<<gemm_grid, blk, 0, stream>>>(U1, W1r, b1r, H, n);
    segsum_bf16<<<seg_grid, blk, 0, stream>>>(H, rpr, esrcr, out_i, n);
}

// Round 4
// 414.949 us; speedup vs baseline: 8.1412x; 1.2157x over previous
//
#include <hip/hip_runtime.h>

#define D 128
#define RPB_BITS 9          // 512 rows per bucket; n<=131072 -> <=256 buckets
#define CH 8192             // edges per bucket_scatter block

typedef __attribute__((ext_vector_type(8))) short bf16x8;
typedef __attribute__((ext_vector_type(4))) float f32x4;

static __device__ __forceinline__ unsigned short f2bf(float f) {
    union { float f; unsigned u; } v; v.f = f;
    unsigned r = (v.u + 0x7fffu + ((v.u >> 16) & 1u)) >> 16;   // RNE
    return (unsigned short)r;
}
static __device__ __forceinline__ float bf2f(unsigned short s) {
    union { unsigned u; float f; } v; v.u = ((unsigned)s) << 16;
    return v.f;
}

// ---------------- GEMM building blocks (BM=32, BN=128, K=128) ----------------
static __device__ __forceinline__ void stage_W(
    const float* __restrict__ W, unsigned short* __restrict__ Wh, int w, int l)
{
    const int n = ((w & 1) << 6) + l;
    #pragma unroll
    for (int i = 0; i < 8; ++i) {
        const int k0 = ((w >> 1) << 3) + (i << 4);
        bf16x8 hv;
        #pragma unroll
        for (int j = 0; j < 8; ++j)
            hv[j] = (short)f2bf(W[(size_t)(k0 + j) * D + n]);
        *(bf16x8*)&Wh[n * D + (k0 ^ ((n & 7) << 3))] = hv;
    }
}

static __device__ __forceinline__ void stage_X(
    const float* __restrict__ X, unsigned short* Xh, unsigned short* Xl,
    int row0, int nrows, int w, int l)
{
    const int k0 = (l & 15) << 3;
    #pragma unroll
    for (int i = 0; i < 2; ++i) {
        const int r = ((w + (i << 2)) << 2) + (l >> 4);   // 0..31
        bf16x8 hv, lv;
        if (row0 + r < nrows) {
            const float* xp = X + (size_t)(row0 + r) * D + k0;
            #pragma unroll
            for (int j = 0; j < 8; ++j) {
                float x = xp[j];
                unsigned short h = f2bf(x);
                hv[j] = (short)h;
                lv[j] = (short)f2bf(x - bf2f(h));   // split-bf16 residual
            }
        } else {
            #pragma unroll
            for (int j = 0; j < 8; ++j) { hv[j] = 0; lv[j] = 0; }
        }
        const int sw = k0 ^ ((r & 7) << 3);
        *(bf16x8*)&Xh[r * D + sw] = hv;
        *(bf16x8*)&Xl[r * D + sw] = lv;
    }
}

static __device__ __forceinline__ void mfma_compute(
    const unsigned short* Xh, const unsigned short* Xl, const unsigned short* Wh,
    f32x4 acc[4], int w, int l)
{
    const int rtile = (w >> 1) << 4;
    const int c0 = (w & 1) << 6;
    const int ra = rtile + (l & 15);
    #pragma unroll
    for (int kb = 0; kb < 4; ++kb) {
        const int kk0 = (kb << 5) + ((l >> 4) << 3);
        const int swa = kk0 ^ ((ra & 7) << 3);
        const bf16x8 ah = *(const bf16x8*)&Xh[ra * D + swa];
        const bf16x8 al = *(const bf16x8*)&Xl[ra * D + swa];
        #pragma unroll
        for (int ct = 0; ct < 4; ++ct) {
            const int n = c0 + (ct << 4) + (l & 15);
            const bf16x8 bh = *(const bf16x8*)&Wh[n * D + (kk0 ^ ((n & 7) << 3))];
            acc[ct] = __builtin_amdgcn_mfma_f32_16x16x32_bf16(ah, bh, acc[ct], 0, 0, 0);
            acc[ct] = __builtin_amdgcn_mfma_f32_16x16x32_bf16(al, bh, acc[ct], 0, 0, 0);
        }
    }
}

static __device__ __forceinline__ void epilogue_store(
    const f32x4 acc[4], const float* __restrict__ bias,
    unsigned short* __restrict__ H, int row0, int nrows, int w, int l)
{
    const int rtile = (w >> 1) << 4;
    const int c0 = (w & 1) << 6;
    #pragma unroll
    for (int ct = 0; ct < 4; ++ct) {
        const int col = c0 + (ct << 4) + (l & 15);
        const float bv = bias[col];
        #pragma unroll
        for (int j = 0; j < 4; ++j) {
            const int r = row0 + rtile + ((l >> 4) << 2) + j;
            if (r < nrows)
                H[(size_t)r * D + col] = f2bf(fmaxf(acc[ct][j] + bv, 0.f));
        }
    }
}

// ---------------- K1: GEMM0 blocks + bucket-prehist blocks fused ----------------
__global__ __launch_bounds__(256) void gemm0_prehist(
    const float* __restrict__ X, const float* __restrict__ W,
    const float* __restrict__ bias, unsigned short* __restrict__ H, int nrows,
    int gemm_grid,
    const int* __restrict__ dstf, const int* __restrict__ dstr,
    int Ef, int Er, int* __restrict__ gbc)
{
    __shared__ unsigned short Xh[32 * D];
    __shared__ unsigned short Xl[32 * D];
    __shared__ unsigned short Wh[128 * D];
    __shared__ int lcnt[512];
    const int tid = threadIdx.x;
    if ((int)blockIdx.x < gemm_grid) {
        const int w = tid >> 6, l = tid & 63;
        const int row0 = blockIdx.x * 32;
        stage_W(W, Wh, w, l);
        stage_X(X, Xh, Xl, row0, nrows, w, l);
        __syncthreads();
        f32x4 acc[4] = {};
        mfma_compute(Xh, Xl, Wh, acc, w, l);
        epilogue_store(acc, bias, H, row0, nrows, w, l);
    } else {
        lcnt[tid] = 0; lcnt[tid + 256] = 0;
        __syncthreads();
        const int nb = gridDim.x - gemm_grid;
        const int bid = blockIdx.x - gemm_grid;
        const int tot = Ef + Er;
        for (int i = bid * 256 + tid; i < tot; i += nb * 256) {
            int idx = (i < Ef) ? (dstf[i] >> RPB_BITS)
                               : (256 + (dstr[i - Ef] >> RPB_BITS));
            atomicAdd(&lcnt[idx], 1);
        }
        __syncthreads();
        if (lcnt[tid])       atomicAdd(&gbc[tid],       lcnt[tid]);
        if (lcnt[tid + 256]) atomicAdd(&gbc[tid + 256], lcnt[tid + 256]);
    }
}

// ---------------- K2: per-rel exclusive scan of 256 bucket counts ----------------
__global__ void scan_buckets(const int* __restrict__ gbc, int* __restrict__ gbase,
                             int* __restrict__ gcur, int* rpf_n, int* rpr_n,
                             int Ef, int Er)
{
    __shared__ int ts[256];
    const int t = threadIdx.x;
    for (int r = 0; r < 2; ++r) {
        int v = gbc[r * 256 + t];
        ts[t] = v; __syncthreads();
        int incl = v;
        for (int o = 1; o < 256; o <<= 1) {
            int y = (t >= o) ? ts[t - o] : 0;
            __syncthreads();
            incl += y; ts[t] = incl;
            __syncthreads();
        }
        gbase[r * 256 + t] = incl - v;
        gcur[r * 256 + t]  = incl - v;
        __syncthreads();
    }
    if (t == 0) { *rpf_n = Ef; *rpr_n = Er; }
}

// ---------------- K3: scatter edges into bucket-major packed form ----------------
// pk word = src | (local_row << 18); src < 2^18, local_row < 512
__global__ __launch_bounds__(256) void bucket_scatter(
    const int* __restrict__ eif, const int* __restrict__ eir,
    int Ef, int Er, int chunks_f,
    int* __restrict__ gcur,
    unsigned* __restrict__ pk_f, unsigned* __restrict__ pk_r)
{
    __shared__ int cnt[256], off[256];
    const int t = threadIdx.x;
    const int cid = blockIdx.x;
    const int *src, *dst; unsigned* pk; int* cur; int base, E;
    if (cid < chunks_f) { base = cid * CH;              E = Ef; src = eif; dst = eif + Ef; pk = pk_f; cur = gcur; }
    else                { base = (cid - chunks_f) * CH; E = Er; src = eir; dst = eir + Er; pk = pk_r; cur = gcur + 256; }
    cnt[t] = 0;
    __syncthreads();
    for (int k = 0; k < CH / 256; ++k) {
        int e = base + t + k * 256;
        if (e < E) atomicAdd(&cnt[dst[e] >> RPB_BITS], 1);
    }
    __syncthreads();
    { int c = cnt[t]; if (c) off[t] = atomicAdd(&cur[t], c); }
    __syncthreads();
    for (int k = 0; k < CH / 256; ++k) {
        int e = base + t + k * 256;
        if (e < E) {
            int d = dst[e];
            int p = atomicAdd(&off[d >> RPB_BITS], 1);
            pk[p] = (unsigned)src[e] | ((unsigned)(d & 511) << 18);
        }
    }
}

// ---------------- K4: per-bucket CSR finalize (rowptr + esrc) ----------------
__global__ __launch_bounds__(256) void csr_finalize(
    const unsigned* __restrict__ pk_f, const unsigned* __restrict__ pk_r,
    const int* __restrict__ gbase, int Ef, int Er,
    int* __restrict__ rpf, int* __restrict__ rpr,
    int* __restrict__ esf, int* __restrict__ esr, int n)
{
    __shared__ int deg[512], cur[512], ts[256];
    const int t = threadIdx.x;
    const int rel = (int)blockIdx.x >> 8;
    const int b = (int)blockIdx.x & 255;
    const unsigned* pk = rel ? pk_r : pk_f;
    int* rp = rel ? rpr : rpf;
    int* es = rel ? esr : esf;
    const int E = rel ? Er : Ef;
    const int* gb = gbase + rel * 256;
    const int beg = gb[b];
    const int end = (b == 255) ? E : gb[b + 1];
    deg[t] = 0; deg[t + 256] = 0;
    __syncthreads();
    for (int j = beg + t; j < end; j += 256)
        atomicAdd(&deg[pk[j] >> 18], 1);
    __syncthreads();
    const int a0 = deg[2 * t], a1 = deg[2 * t + 1];
    const int s = a0 + a1;
    ts[t] = s; __syncthreads();
    int incl = s;
    for (int o = 1; o < 256; o <<= 1) {
        int y = (t >= o) ? ts[t - o] : 0;
        __syncthreads();
        incl += y; ts[t] = incl;
        __syncthreads();
    }
    const int ex = incl - s;
    const int row0 = b << RPB_BITS;
    if (row0 + 2 * t < n)     rp[row0 + 2 * t]     = beg + ex;
    if (row0 + 2 * t + 1 < n) rp[row0 + 2 * t + 1] = beg + ex + a0;
    cur[2 * t] = ex; cur[2 * t + 1] = ex + a0;
    __syncthreads();
    for (int j = beg + t; j < end; j += 256) {
        unsigned v = pk[j];
        int p = atomicAdd(&cur[v >> 18], 1);
        es[beg + p] = (int)(v & 0x3ffffu);
    }
}

// ---------------- segmented sum over bf16 H -> fp32 out ----------------
static __device__ __forceinline__ void segsum_row(
    const unsigned short* __restrict__ H, const int* __restrict__ rp,
    const int* __restrict__ es, float* __restrict__ out, int row, int lane16)
{
    const int c = lane16 << 3;
    float a[8] = {0.f,0.f,0.f,0.f,0.f,0.f,0.f,0.f};
    const int beg = rp[row], end = rp[row + 1];
    int sNext = (beg < end) ? es[beg] : 0;
    for (int j = beg; j < end; ++j) {
        const int s = sNext;
        sNext = (j + 1 < end) ? es[j + 1] : 0;   // prefetch next index
        const uint4 v = *(const uint4*)(H + (size_t)s * D + c);
        const unsigned dw[4] = {v.x, v.y, v.z, v.w};
        #pragma unroll
        for (int q = 0; q < 4; ++q) {
            union { unsigned u; float f; } lo, hi;
            lo.u = dw[q] << 16;
            hi.u = dw[q] & 0xffff0000u;
            a[2 * q]     += lo.f;
            a[2 * q + 1] += hi.f;
        }
    }
    float4 o0 = {a[0], a[1], a[2], a[3]};
    float4 o1 = {a[4], a[5], a[6], a[7]};
    *(float4*)(out + (size_t)row * D + c)     = o0;
    *(float4*)(out + (size_t)row * D + c + 4) = o1;
}

__global__ __launch_bounds__(256) void segsum_bf16(
    const unsigned short* __restrict__ H, const int* __restrict__ rowptr,
    const int* __restrict__ esrc, float* __restrict__ out, int nrows)
{
    const int t = blockIdx.x * 256 + threadIdx.x;
    const int row = t >> 4;
    if (row >= nrows) return;
    segsum_row(H, rowptr, esrc, out, row, t & 15);
}

__global__ __launch_bounds__(256) void segsum_bf16_dual(
    const unsigned short* __restrict__ Hf, const int* __restrict__ rpf,
    const int* __restrict__ esf, float* __restrict__ ou,
    const unsigned short* __restrict__ Hr, const int* __restrict__ rpr,
    const int* __restrict__ esr, float* __restrict__ oi,
    int nrows, int seg_grid)
{
    int bid = blockIdx.x;
    const unsigned short* H; const int* rp; const int* es; float* out;
    if (bid < seg_grid) { H = Hf; rp = rpf; es = esf; out = ou; }
    else { bid -= seg_grid; H = Hr; rp = rpr; es = esr; out = oi; }
    const int t = bid * 256 + threadIdx.x;
    const int row = t >> 4;
    if (row >= nrows) return;
    segsum_row(H, rp, es, out, row, t & 15);
}

// ---------------- dual GEMM: H1=relu(X@W1+b1), H2=relu(X@W2+b2) ----------------
__global__ __launch_bounds__(256) void gemm_relu_bf16_dual(
    const float* __restrict__ X,
    const float* __restrict__ W1, const float* __restrict__ b1, unsigned short* __restrict__ H1,
    const float* __restrict__ W2, const float* __restrict__ b2, unsigned short* __restrict__ H2,
    int nrows)
{
    __shared__ unsigned short Xh[32 * D];
    __shared__ unsigned short Xl[32 * D];
    __shared__ unsigned short Wh[2][128 * D];   // 64 KB
    const int tid = threadIdx.x;
    const int w = tid >> 6, l = tid & 63;
    const int row0 = blockIdx.x * 32;
    stage_W(W1, Wh[0], w, l);
    stage_W(W2, Wh[1], w, l);
    stage_X(X, Xh, Xl, row0, nrows, w, l);
    __syncthreads();
    {
        f32x4 acc[4] = {};
        mfma_compute(Xh, Xl, Wh[0], acc, w, l);
        epilogue_store(acc, b1, H1, row0, nrows, w, l);
    }
    {
        f32x4 acc[4] = {};
        mfma_compute(Xh, Xl, Wh[1], acc, w, l);
        epilogue_store(acc, b2, H2, row0, nrows, w, l);
    }
}

// ---------------- host orchestration ----------------
static inline size_t align16(size_t x) { return (x + 15) & ~(size_t)15; }

extern "C" void kernel_launch(void* const* d_in, const int* in_sizes, int n_in,
                              void* d_out, int out_size, void* d_ws, size_t ws_size,
                              hipStream_t stream)
{
    const float* x_user = (const float*)d_in[0];
    // d_in[1] = x_item: unused (both relations source from users)
    const int*   ei_fol = (const int*)d_in[2];
    const int*   ei_rat = (const int*)d_in[3];
    const float* W0f = (const float*)d_in[4];
    const float* b0f = (const float*)d_in[5];
    // d_in[6..7]: W0_rates/b0_rates dead (layer-0 item output never consumed)
    const float* W1f = (const float*)d_in[8];
    const float* b1f = (const float*)d_in[9];
    const float* W1r = (const float*)d_in[10];
    const float* b1r = (const float*)d_in[11];

    const int n  = in_sizes[0] / D;   // 100000  (n < 2^18 and n <= 131072 assumed)
    const int Ef = in_sizes[2] / 2;   // 600000
    const int Er = in_sizes[3] / 2;

    float* out_u = (float*)d_out;
    float* out_i = out_u + (size_t)n * D;
    float* U1 = out_i;   // fp32 layer-0 user output staged in out_i's slot

    // workspace (~62 MB)
    char* ws = (char*)d_ws;
    size_t off = 0;
    unsigned short* HA = (unsigned short*)(ws + off); off = align16(off + (size_t)n * D * 2);  // H0, then H1f
    unsigned short* HB = (unsigned short*)(ws + off); off = align16(off + (size_t)n * D * 2);  // H1r
    int* rpf   = (int*)(ws + off); off = align16(off + (size_t)(n + 1) * 4);
    int* rpr   = (int*)(ws + off); off = align16(off + (size_t)(n + 1) * 4);
    int* esf   = (int*)(ws + off); off = align16(off + (size_t)Ef * 4);
    int* esr   = (int*)(ws + off); off = align16(off + (size_t)Er * 4);
    unsigned* pkf = (unsigned*)(ws + off); off = align16(off + (size_t)Ef * 4);
    unsigned* pkr = (unsigned*)(ws + off); off = align16(off + (size_t)Er * 4);
    int* gbc   = (int*)(ws + off); off = align16(off + 512 * 4);
    int* gbase = (int*)(ws + off); off = align16(off + 512 * 4);
    int* gcur  = (int*)(ws + off); off = align16(off + 512 * 4);
    (void)ws_size;

    const dim3 blk(256);
    const int gemm_grid = (n + 31) / 32;                           // 3125
    const int PB = 320;                                            // prehist blocks
    const int chunks_f = (Ef + CH - 1) / CH;                       // 74
    const int chunks_r = (Er + CH - 1) / CH;
    const int seg_grid = (int)(((long long)n * 16 + 255) / 256);   // 6250

    hipMemsetAsync(gbc, 0, 512 * sizeof(int), stream);

    // K1: GEMM0 (H0 = relu(x_user@W0f+b0f)) fused with bucket prehist
    gemm0_prehist<<<gemm_grid + PB, blk, 0, stream>>>(
        x_user, W0f, b0f, HA, n, gemm_grid, ei_fol + Ef, ei_rat + Er, Ef, Er, gbc);
    // K2..K4: CSR build for both relations
    scan_buckets<<<1, 256, 0, stream>>>(gbc, gbase, gcur, rpf + n, rpr + n, Ef, Er);
    bucket_scatter<<<chunks_f + chunks_r, blk, 0, stream>>>(
        ei_fol, ei_rat, Ef, Er, chunks_f, gcur, pkf, pkr);
    csr_finalize<<<512, blk, 0, stream>>>(pkf, pkr, gbase, Ef, Er, rpf, rpr, esf, esr, n);

    // Layer 0 aggregate: U1 = segsum_f(H0)
    segsum_bf16<<<seg_grid, blk, 0, stream>>>(HA, rpf, esf, U1, n);

    // Layer 1: both GEMMs in one pass (HA <- H1f overwrites H0; HB <- H1r)
    gemm_relu_bf16_dual<<<gemm_grid, blk, 0, stream>>>(U1, W1f, b1f, HA, W1r, b1r, HB, n);

    // Final aggregates: out_u = segsum_f(H1f), out_i = segsum_r(H1r)
    segsum_bf16_dual<<<2 * seg_grid, blk, 0, stream>>>(
        HA, rpf, esf, out_u, HB, rpr, esr, out_i, n, seg_grid);
}